// Round 8
// baseline (191.073 us; speedup 1.0000x reference)
//
#include <hip/hip_runtime.h>
#include <stdint.h>

#define V_DIM 32000
#define M_TOT 4096      // B*S
#define NF 128          // 2*n_freq
#define NC 256          // channels
#define BM 64           // M-tile
#define BK 32           // K-step
#define NSPL 16
#define THREADS 256

typedef __bf16 bf16x8 __attribute__((ext_vector_type(8)));
typedef float f32x4 __attribute__((ext_vector_type(4)));

__device__ __forceinline__ unsigned short f2bf(float f) {  // RNE (table build)
  unsigned int u = __float_as_uint(f);
  u += 0x7FFFu + ((u >> 16) & 1u);
  return (unsigned short)(u >> 16);
}

// two fp32 -> packed bf16x2 by truncation (1 v_perm); measured safe (absmax 1.0 << 2.96)
__device__ __forceinline__ unsigned int pk2(float lo, float hi) {
  return __builtin_amdgcn_perm(__float_as_uint(hi), __float_as_uint(lo), 0x07060302u);
}

__device__ __forceinline__ void gllA(const float* g, const float* l) {
  __builtin_amdgcn_global_load_lds(
      (const __attribute__((address_space(1))) void*)g,
      (__attribute__((address_space(3))) void*)l, 16, 0, 0);
}
__device__ __forceinline__ void gllB(const unsigned short* g, const unsigned short* l) {
  __builtin_amdgcn_global_load_lds(
      (const __attribute__((address_space(1))) void*)g,
      (__attribute__((address_space(3))) void*)l, 16, 0, 0);
}

// ---------------- Stage 0: DFT table in LDS-LINEAR-STAGING order (same as R7) --------
// per step: 512 chunks of 16B, id = q*256 + wave*64 + lane -> LDS offset id*16.
// col = q*64 + wave*16 + (lane>>2); baked swizzle kg = (lane&3) ^ m(col),
// m(col) = (col + (col>>2)) & 3. Chunk elem e -> T_log[col][cstep*32 + kg*8 + e].
// T_log[f][v] = cos(2pi(f+1)v/V) (f<64), -sin(2pi(f-63)v/V) (f>=64)
__global__ __launch_bounds__(256) void build_table(unsigned short* __restrict__ T) {
  int id = blockIdx.x * 256 + threadIdx.x;
  if (id >= 512 * 1000) return;
  int cstep = id >> 9;
  int r = id & 511;
  int q = r >> 8;
  int tt = r & 255;
  int w = tt >> 6, l = tt & 63;
  int col = q * 64 + w * 16 + (l >> 2);
  int m = (col + (col >> 2)) & 3;
  int kg = (l & 3) ^ m;
  int k = (col < 64) ? (col + 1) : (col - 63);
  bool is_cos = (col < 64);
  int vb = cstep * 32 + kg * 8;
  const float w0 = 6.283185307179586f / (float)V_DIM;
  union { unsigned short us[8]; int4 v; } u;
  #pragma unroll
  for (int e = 0; e < 8; ++e) {
    int mm = (k * (vb + e)) % V_DIM;              // exact range reduction
    float s, cc;
    __sincosf((float)mm * w0, &s, &cc);
    u.us[e] = f2bf(is_cos ? cc : -s);
  }
  *reinterpret_cast<int4*>(T + (size_t)id * 8) = u.v;
}

// ---------------- Stage 1: P[ks] = x_tile @ T_chunk^T ----------------
// 3-buffer ring, counted vmcnt(4): the vmem pipe NEVER drains to 0 in the main loop.
// Per step: [vmcnt(4); s_barrier] -> issue stage(s+2) -> compute buf[s%3].
__global__ __launch_bounds__(THREADS) void gemm1(
    const float* __restrict__ x, const unsigned short* __restrict__ T,
    float* __restrict__ P) {
  __shared__ __align__(16) float As[3][2048];           // fp32 A tiles, 8 KB each
  __shared__ __align__(16) unsigned short Bs[3][4096];  // bf16 B tiles, 8 KB each

  // XCD pinning: xcd j = b&7 sees only ks in {j, j+8} -> T slice stays L2-hot
  const int b = blockIdx.x;
  const int j = b & 7, i = b >> 3;      // i: 0..127
  const int ks = j + 8 * (i & 1);       // 0..15
  const int mt = i >> 1;                // 0..63
  const int m0 = mt * BM;

  const int basek = 1000 / NSPL, remk = 1000 % NSPL;   // 62, 8
  const int steps = basek + (ks < remk);
  const int start = ks * basek + (ks < remk ? ks : remk);

  const int t = threadIdx.x;
  const int lane = t & 63, wave = t >> 6;
  const int wm = wave >> 1, wn = wave & 1;   // wave tile 32m x 64n
  const int kgl = lane >> 4, rl = lane & 15;

  // A staging: 2 gllA/wave, instr i covers rows i*32 + wave*8 + rsub, 8 chunks/row.
  // XOR bank swizzle baked into per-lane GLOBAL source: csub = (lane&7) ^ rsub.
  const int rsub = lane >> 3;
  const int csub = (lane & 7) ^ rsub;
  const float* xbase = x + (size_t)(m0 + wave * 8 + rsub) * V_DIM + csub * 4
                         + (size_t)start * BK;
  const unsigned short* Tb = T + (size_t)start * 4096;

  f32x4 acc[2][4];
  #pragma unroll
  for (int a = 0; a < 2; ++a)
    #pragma unroll
    for (int c = 0; c < 4; ++c) acc[a][c] = (f32x4){0.f, 0.f, 0.f, 0.f};

  auto stage = [&](int s, int buf) {          // 4 vmem instructions per wave
    const float* xs = xbase + (size_t)s * BK;
    gllA(xs,                      &As[buf][wave * 256]);
    gllA(xs + (size_t)32 * V_DIM, &As[buf][1024 + wave * 256]);
    const unsigned short* ts = Tb + (size_t)s * 4096 + t * 8;
    gllB(ts,        &Bs[buf][wave * 512]);
    gllB(ts + 2048, &Bs[buf][2048 + wave * 512]);
  };

  // lane-constant pieces of the B read address
  const int mB = (rl + (rl >> 2)) & 3;        // == m(col) for col = wn*64+nf*16+rl
  const int bslot = (kgl ^ mB) * 8;           // ushort offset within col

  // ---- prologue: two stages in flight
  stage(0, 0);
  stage(1, 1);

  int cur = 0, nx1 = 1, nx2 = 2;
  for (int s = 0; s < steps; ++s) {
    // own stage(s) complete; stage(s+1) stays in flight ACROSS the barrier
    if (s + 1 < steps) asm volatile("s_waitcnt vmcnt(4)" ::: "memory");
    else               asm volatile("s_waitcnt vmcnt(0)" ::: "memory");
    asm volatile("s_barrier" ::: "memory");   // all waves: stage(s) done, buf[nx2] free
    if (s + 2 < steps) stage(s + 2, nx2);

    // B fragments
    bf16x8 bfr[4];
    #pragma unroll
    for (int nf = 0; nf < 4; ++nf) {
      int col = wn * 64 + nf * 16 + rl;
      bfr[nf] = *reinterpret_cast<const bf16x8*>(&Bs[cur][col * 32 + bslot]);
    }
    // A fragments (fp32 -> bf16 in reg) + MFMA
    #pragma unroll
    for (int mf = 0; mf < 2; ++mf) {
      int row = wm * 32 + mf * 16 + rl;
      int base = row * 32;
      float4 lo = *reinterpret_cast<const float4*>(
          &As[cur][base + (((2 * kgl) ^ (row & 7)) * 4)]);
      float4 hi = *reinterpret_cast<const float4*>(
          &As[cur][base + (((2 * kgl + 1) ^ (row & 7)) * 4)]);
      union { uint4 u; bf16x8 v; } a8;
      a8.u.x = pk2(lo.x, lo.y); a8.u.y = pk2(lo.z, lo.w);
      a8.u.z = pk2(hi.x, hi.y); a8.u.w = pk2(hi.z, hi.w);
      #pragma unroll
      for (int nf = 0; nf < 4; ++nf)
        acc[mf][nf] = __builtin_amdgcn_mfma_f32_16x16x32_bf16(
            a8.v, bfr[nf], acc[mf][nf], 0, 0, 0);
    }

    int tmp = cur; cur = nx1; nx1 = nx2; nx2 = tmp;   // rotate ring
  }

  // ---- epilogue: partial [64 x 128] tile for this k-split
  float* Pp = P + ((size_t)ks * M_TOT + m0) * NF;
  const int r0 = (lane >> 4) * 4;
  const int col = lane & 15;
  #pragma unroll
  for (int mf = 0; mf < 2; ++mf)
    #pragma unroll
    for (int nf = 0; nf < 4; ++nf)
      #pragma unroll
      for (int q = 0; q < 4; ++q) {
        int row = wm * 32 + mf * 16 + r0 + q;
        int n = wn * 64 + nf * 16 + col;
        Pp[(size_t)row * NF + n] = acc[mf][nf][q];
      }
}

// ---------------- Stage 2: out = (sum_s P[s]) @ W^T ----------------
__global__ __launch_bounds__(256) void gemm2(
    const float* __restrict__ P, const float* __restrict__ W,
    float* __restrict__ out, int NS) {
  __shared__ __align__(16) float Xr[8][NF];
  const int mb = blockIdx.x * 8;
  const int t = threadIdx.x;

  #pragma unroll
  for (int i = 0; i < 4; ++i) {
    int idx = t + i * 256;           // 8 rows x 128 freqs
    int r = idx >> 7, f = idx & 127;
    float s = 0.f;
    for (int sp = 0; sp < NS; ++sp)
      s += P[((size_t)sp * M_TOT + mb + r) * NF + f];
    Xr[r][f] = s;
  }
  __syncthreads();

  const float4* Wr = reinterpret_cast<const float4*>(W + (size_t)t * NF);
  float accr[8];
  #pragma unroll
  for (int r = 0; r < 8; ++r) accr[r] = 0.f;

  for (int f4 = 0; f4 < NF / 4; ++f4) {
    float4 w = Wr[f4];
    #pragma unroll
    for (int r = 0; r < 8; ++r) {
      float4 xv = *reinterpret_cast<const float4*>(&Xr[r][f4 * 4]);
      accr[r] += xv.x * w.x + xv.y * w.y + xv.z * w.z + xv.w * w.w;
    }
  }
  #pragma unroll
  for (int r = 0; r < 8; ++r)
    out[(size_t)(mb + r) * NC + t] = accr[r];
}

extern "C" void kernel_launch(void* const* d_in, const int* in_sizes, int n_in,
                              void* d_out, int out_size, void* d_ws, size_t ws_size,
                              hipStream_t stream) {
  const float* x = (const float*)d_in[0];
  const float* w = (const float*)d_in[1];
  float* out = (float*)d_out;

  unsigned short* T = (unsigned short*)d_ws;
  const size_t t_bytes = (size_t)NF * V_DIM * sizeof(unsigned short); // 8,192,000
  float* P = (float*)((char*)d_ws + t_bytes);
  // ws need: 8 MB (T) + 16 * 2 MiB (P) = 40 MB (proven available in R4).

  build_table<<<dim3(2000), dim3(256), 0, stream>>>(T);
  gemm1<<<dim3(64 * NSPL), dim3(THREADS), 0, stream>>>(x, T, P);
  gemm2<<<dim3(M_TOT / 8), dim3(256), 0, stream>>>(P, w, out, NSPL);
}

// Round 9
// 165.496 us; speedup vs baseline: 1.1545x; 1.1545x over previous
//
#include <hip/hip_runtime.h>
#include <stdint.h>

#define V_DIM 32000
#define M_TOT 4096      // B*S
#define NF 128          // 2*n_freq
#define NC 256          // channels
#define BM 64           // M-tile
#define BK 64           // K-step in floats: 256B contiguous per row per step
#define K64 500         // V_DIM / BK
#define NSPL 16
#define THREADS 256

typedef __bf16 bf16x8 __attribute__((ext_vector_type(8)));
typedef float f32x4 __attribute__((ext_vector_type(4)));

__device__ __forceinline__ unsigned short f2bf(float f) {  // RNE (table build)
  unsigned int u = __float_as_uint(f);
  u += 0x7FFFu + ((u >> 16) & 1u);
  return (unsigned short)(u >> 16);
}

// two fp32 -> packed bf16x2 by truncation (1 v_perm); measured safe (absmax 1.0 << 2.96)
__device__ __forceinline__ unsigned int pk2(float lo, float hi) {
  return __builtin_amdgcn_perm(__float_as_uint(hi), __float_as_uint(lo), 0x07060302u);
}

__device__ __forceinline__ void gllA(const float* g, const float* l) {
  __builtin_amdgcn_global_load_lds(
      (const __attribute__((address_space(1))) void*)g,
      (__attribute__((address_space(3))) void*)l, 16, 0, 0);
}
__device__ __forceinline__ void gllB(const unsigned short* g, const unsigned short* l) {
  __builtin_amdgcn_global_load_lds(
      (const __attribute__((address_space(1))) void*)g,
      (__attribute__((address_space(3))) void*)l, 16, 0, 0);
}

// ---------------- Stage 0: DFT table, BK=64 staging order + baked col-rotation -------
// Per step: 1024 chunks of 16B (8 bf16), staged linearly. chunk id r in step:
//   col = r>>3 (0..127), phys = r&7; logical chunk c = (phys - col) & 7
//   elem e -> T_log[col][step*64 + c*8 + e]
//   T_log[f][v] = cos(2pi(f+1)v/V) (f<64), -sin(2pi(f-63)v/V) (f>=64)
// Rotation makes the gemm1 B-fragment read bank-uniform; matching read applies
// chunk' = (chunk + col) & 7  (both-sides-or-neither, rule 21).
__global__ __launch_bounds__(256) void build_table(unsigned short* __restrict__ T) {
  int id = blockIdx.x * 256 + threadIdx.x;
  if (id >= 1024 * K64) return;                 // 512000
  int step = id >> 10;
  int r = id & 1023;
  int col = r >> 3;
  int phys = r & 7;
  int c = (phys - col) & 7;
  int k = (col < 64) ? (col + 1) : (col - 63);
  bool is_cos = (col < 64);
  int vb = step * 64 + c * 8;
  const float w0 = 6.283185307179586f / (float)V_DIM;
  union { unsigned short us[8]; int4 v; } u;
  #pragma unroll
  for (int e = 0; e < 8; ++e) {
    int mm = (k * (vb + e)) % V_DIM;            // exact range reduction
    float s, cc;
    __sincosf((float)mm * w0, &s, &cc);
    u.us[e] = f2bf(is_cos ? cc : -s);
  }
  *reinterpret_cast<int4*>(T + (size_t)id * 8) = u.v;
}

// ---------------- Stage 1: P[ks] = x_tile @ T_chunk^T (BK=64, 256B runs) ------------
__global__ __launch_bounds__(THREADS) void gemm1(
    const float* __restrict__ x, const unsigned short* __restrict__ T,
    float* __restrict__ P) {
  __shared__ __align__(16) float As[2][4096];           // [64 rows][64 k] fp32, 16KB
  __shared__ __align__(16) unsigned short Bs[2][8192];  // [128 col][64 k] bf16, 16KB

  // XCD pinning: xcd j = b&7 sees only ks in {j, j+8}
  const int b = blockIdx.x;
  const int j = b & 7, i = b >> 3;      // i: 0..127
  const int ks = j + 8 * (i & 1);       // 0..15
  const int mt = i >> 1;                // 0..63
  const int m0 = mt * BM;

  const int basek = K64 / NSPL, remk = K64 % NSPL;   // 31, 4
  const int steps = basek + (ks < remk);
  const int start = ks * basek + (ks < remk ? ks : remk);

  const int t = threadIdx.x;
  const int lane = t & 63, wave = t >> 6;
  const int wm = wave >> 1, wn = wave & 1;   // wave tile 32m x 64n
  const int kgl = lane >> 4, rl = lane & 15;

  // A source pointers: gllA instr i covers rows i*16 + wave*4 + (lane>>4),
  // 16 lanes/row = 256B contiguous. Per-lane chunk rotated: c = ((lane&15) - row)&15
  // so LDS slot (row, phys=lane&15) holds logical chunk (phys - row)&15.
  const float* xsrc0; const float* xsrc1; const float* xsrc2; const float* xsrc3;
  {
    int rl4 = lane >> 4, c4 = lane & 15;
    #define MKSRC(I, DST)                                                     \
      { int r_loc = (I)*16 + wave * 4 + rl4;                                  \
        int c = (c4 - r_loc) & 15;                                            \
        DST = x + (size_t)(m0 + r_loc) * V_DIM + (size_t)start * BK + c * 4; }
    MKSRC(0, xsrc0) MKSRC(1, xsrc1) MKSRC(2, xsrc2) MKSRC(3, xsrc3)
    #undef MKSRC
  }
  const unsigned short* tsrc = T + (size_t)start * 8192 + (size_t)(wave * 64 + lane) * 8;

  f32x4 acc[2][4];
  #pragma unroll
  for (int a = 0; a < 2; ++a)
    #pragma unroll
    for (int c = 0; c < 4; ++c) acc[a][c] = (f32x4){0.f, 0.f, 0.f, 0.f};

  auto stage = [&](int s, int buf) {          // 8 vmem instr per wave
    const size_t so = (size_t)s * BK;
    gllA(xsrc0 + so, &As[buf][(0 * 16 + wave * 4) * 64]);
    gllA(xsrc1 + so, &As[buf][(1 * 16 + wave * 4) * 64]);
    gllA(xsrc2 + so, &As[buf][(2 * 16 + wave * 4) * 64]);
    gllA(xsrc3 + so, &As[buf][(3 * 16 + wave * 4) * 64]);
    const unsigned short* ts = tsrc + (size_t)s * 8192;
    #pragma unroll
    for (int q = 0; q < 4; ++q)
      gllB(ts + q * 2048, &Bs[buf][q * 2048 + wave * 512]);
  };

  stage(0, 0);
  __syncthreads();

  for (int s = 0; s < steps; ++s) {
    const int cur = s & 1, nxt = cur ^ 1;
    if (s + 1 < steps) stage(s + 1, nxt);   // in flight across the compute

    #pragma unroll
    for (int kk = 0; kk < 2; ++kk) {
      // B fragments: col*64 ushorts + rotated chunk
      bf16x8 bfr[4];
      #pragma unroll
      for (int nf = 0; nf < 4; ++nf) {
        int col = wn * 64 + nf * 16 + rl;
        int ch = (kk * 4 + kgl + col) & 7;
        bfr[nf] = *reinterpret_cast<const bf16x8*>(&Bs[cur][col * 64 + ch * 8]);
      }
      // A fragments: two rotated 16B chunks -> bf16 pack -> 4 MFMAs
      #pragma unroll
      for (int mf = 0; mf < 2; ++mf) {
        int row = wm * 32 + mf * 16 + rl;
        int c0 = kk * 8 + kgl * 2;
        int plo = (c0 + row) & 15, phi = (c0 + 1 + row) & 15;
        float4 lo = *reinterpret_cast<const float4*>(&As[cur][row * 64 + plo * 4]);
        float4 hi = *reinterpret_cast<const float4*>(&As[cur][row * 64 + phi * 4]);
        union { uint4 u; bf16x8 v; } a8;
        a8.u.x = pk2(lo.x, lo.y); a8.u.y = pk2(lo.z, lo.w);
        a8.u.z = pk2(hi.x, hi.y); a8.u.w = pk2(hi.z, hi.w);
        #pragma unroll
        for (int nf = 0; nf < 4; ++nf)
          acc[mf][nf] = __builtin_amdgcn_mfma_f32_16x16x32_bf16(
              a8.v, bfr[nf], acc[mf][nf], 0, 0, 0);
      }
    }
    __syncthreads();   // drains vmcnt: buf nxt staged, buf cur reads complete
  }

  // ---- epilogue: partial [64 x 128] tile for this k-split
  float* Pp = P + ((size_t)ks * M_TOT + m0) * NF;
  const int r0 = (lane >> 4) * 4;
  const int col = lane & 15;
  #pragma unroll
  for (int mf = 0; mf < 2; ++mf)
    #pragma unroll
    for (int nf = 0; nf < 4; ++nf)
      #pragma unroll
      for (int q = 0; q < 4; ++q) {
        int row = wm * 32 + mf * 16 + r0 + q;
        int n = wn * 64 + nf * 16 + col;
        Pp[(size_t)row * NF + n] = acc[mf][nf][q];
      }
}

// ---------------- Stage 2: out = (sum_s P[s]) @ W^T ----------------
__global__ __launch_bounds__(256) void gemm2(
    const float* __restrict__ P, const float* __restrict__ W,
    float* __restrict__ out, int NS) {
  __shared__ __align__(16) float Xr[8][NF];
  const int mb = blockIdx.x * 8;
  const int t = threadIdx.x;

  #pragma unroll
  for (int i = 0; i < 4; ++i) {
    int idx = t + i * 256;           // 8 rows x 128 freqs
    int r = idx >> 7, f = idx & 127;
    float s = 0.f;
    for (int sp = 0; sp < NS; ++sp)
      s += P[((size_t)sp * M_TOT + mb + r) * NF + f];
    Xr[r][f] = s;
  }
  __syncthreads();

  const float4* Wr = reinterpret_cast<const float4*>(W + (size_t)t * NF);
  float accr[8];
  #pragma unroll
  for (int r = 0; r < 8; ++r) accr[r] = 0.f;

  for (int f4 = 0; f4 < NF / 4; ++f4) {
    float4 w = Wr[f4];
    #pragma unroll
    for (int r = 0; r < 8; ++r) {
      float4 xv = *reinterpret_cast<const float4*>(&Xr[r][f4 * 4]);
      accr[r] += xv.x * w.x + xv.y * w.y + xv.z * w.z + xv.w * w.w;
    }
  }
  #pragma unroll
  for (int r = 0; r < 8; ++r)
    out[(size_t)(mb + r) * NC + t] = accr[r];
}

extern "C" void kernel_launch(void* const* d_in, const int* in_sizes, int n_in,
                              void* d_out, int out_size, void* d_ws, size_t ws_size,
                              hipStream_t stream) {
  const float* x = (const float*)d_in[0];
  const float* w = (const float*)d_in[1];
  float* out = (float*)d_out;

  unsigned short* T = (unsigned short*)d_ws;
  const size_t t_bytes = (size_t)NF * V_DIM * sizeof(unsigned short); // 8,192,000
  float* P = (float*)((char*)d_ws + t_bytes);
  // ws need: 8 MB (T) + 16 * 2 MiB (P) = 40 MB (proven available).

  build_table<<<dim3(2000), dim3(256), 0, stream>>>(T);
  gemm1<<<dim3(64 * NSPL), dim3(THREADS), 0, stream>>>(x, T, P);
  gemm2<<<dim3(M_TOT / 8), dim3(256), 0, stream>>>(P, w, out, NSPL);
}